// Round 14
// baseline (46343.396 us; speedup 1.0000x reference)
//
#include <hip/hip_runtime.h>
#include <math.h>

#define TT  256
#define BB  32
#define EE  1024
#define MM  4096
#define VV  4096
#define BE  (BB*EE)
#define NROWS (TT*BB)
#define EPSF 1.1920929e-07f

typedef _Float16 h2 __attribute__((ext_vector_type(2)));

__device__ inline float dot2f(h2 a, h2 b, float c) {
#if __has_builtin(__builtin_amdgcn_fdot2)
  return __builtin_amdgcn_fdot2(a, b, c, false);
#else
  return c + (float)a[0] * (float)b[0] + (float)a[1] * (float)b[1];
#endif
}

// ---- coherent-point (MALL) data movement: relaxed agent atomics = cache bypass ----
__device__ inline unsigned ldb_u32(const unsigned* p) {
  return __hip_atomic_load((unsigned*)p, __ATOMIC_RELAXED, __HIP_MEMORY_SCOPE_AGENT);
}
__device__ inline void stb_u32(unsigned* p, unsigned v) {
  __hip_atomic_store(p, v, __ATOMIC_RELAXED, __HIP_MEMORY_SCOPE_AGENT);
}
__device__ inline void stb_f32(float* p, float v) {
  __hip_atomic_store(p, v, __ATOMIC_RELAXED, __HIP_MEMORY_SCOPE_AGENT);
}

// ---- fence-free hierarchical grid barrier (fresh counters per barrier) ----
__device__ inline void gbar4(unsigned* cnt, int sidx) {
  __syncthreads();
  if (threadIdx.x == 0) {
    unsigned* base = cnt + (size_t)sidx * 17 * 32;
    unsigned* gp = base + (blockIdx.x & 15) * 32;
    unsigned* mp = base + 16 * 32;
    unsigned old = __hip_atomic_fetch_add(gp, 1u, __ATOMIC_RELAXED,
                                          __HIP_MEMORY_SCOPE_AGENT);
    if (old == 15u)
      __hip_atomic_fetch_add(mp, 1u, __ATOMIC_RELAXED, __HIP_MEMORY_SCOPE_AGENT);
    while (__hip_atomic_load(mp, __ATOMIC_RELAXED, __HIP_MEMORY_SCOPE_AGENT) < 16u)
      __builtin_amdgcn_s_sleep(1);
  }
  __syncthreads();
}

// ---- fc1-like stage, 1024-thread version (R12 flow, half work per thread) ----
// Staging: thread (sb=tid>>5, lane=tid&31) loads ONE float4 (4 elems) per chunk.
// Compute: (b=tid&31, kq=tid>>5 in [0,32)) dots 2 h2 per chunk per col.
// Cross-wave reduction via LDS atomicAdd into red[32][17] (zeroed at entry).
// Seeding: block cu's lane (tid&31)==(cu&31), chunk cu>>5, float4 = cols [4cu,4cu+4).
template<int NR>
__device__ float fc1like(int tid, int cu,
    const float* __restrict__ src, const float* __restrict__ scl,
    const h2* __restrict__ wl, h2* __restrict__ xs, float* __restrict__ red,
    float* __restrict__ ssrow,
    float* __restrict__ seedDst, const float* __restrict__ seedAdd,
    const float* __restrict__ seedBias) {
  const int b = tid & 31, kq = tid >> 5;
  const int sb = tid >> 5, ln = tid & 31;
  const int e2 = ln * 2;                    // h2 position base in chunk
  float ssacc = 0.f;
  float acc[NR];
#pragma unroll
  for (int m = 0; m < NR; ++m) acc[m] = 0.f;
  const int seedChunk = cu >> 5;
  const bool seeder = (seedDst != nullptr) && (ln == (cu & 31));

  // zero the atomic reduction buffer (visible after first sync)
  for (int i = tid; i < 544; i += 1024) red[i] = 0.f;

  float4 v0, c0v;
  auto ldchunk = [&](int c) {
    v0 = *(const float4*)&src[sb * EE + c * 128 + ln * 4];
    c0v = *(const float4*)&scl[c * 128 + ln * 4];
  };
  auto flush = [&](int c) {
    h2* dst = xs + (c & 1) * (64 * 33);
    ssacc += v0.x*v0.x + v0.y*v0.y + v0.z*v0.z + v0.w*v0.w;
    h2 p0, p1;
    p0[0]=(_Float16)(v0.x*c0v.x); p0[1]=(_Float16)(v0.y*c0v.y);
    p1[0]=(_Float16)(v0.z*c0v.z); p1[1]=(_Float16)(v0.w*c0v.w);
    dst[(e2+0)*33+sb]=p0; dst[(e2+1)*33+sb]=p1;
    if (seeder && c == seedChunk) {
      const int e0 = c * 128 + ln * 4;
      float d0 = v0.x + seedBias[e0 + 0];
      float d1 = v0.y + seedBias[e0 + 1];
      float d2 = v0.z + seedBias[e0 + 2];
      float d3 = v0.w + seedBias[e0 + 3];
      if (seedAdd) {
        d0 += seedAdd[sb * EE + e0 + 0];
        d1 += seedAdd[sb * EE + e0 + 1];
        d2 += seedAdd[sb * EE + e0 + 2];
        d3 += seedAdd[sb * EE + e0 + 3];
      }
      stb_f32(&seedDst[sb * EE + e0 + 0], d0);
      stb_f32(&seedDst[sb * EE + e0 + 1], d1);
      stb_f32(&seedDst[sb * EE + e0 + 2], d2);
      stb_f32(&seedDst[sb * EE + e0 + 3], d3);
    }
  };
  ldchunk(0); flush(0);
  __syncthreads();
  for (int c = 0; c < 8; ++c) {
    if (c < 7) ldchunk(c + 1);
    const h2* xb = xs + (c & 1) * (64 * 33);
    h2 x0 = xb[(kq*2+0)*33+b], x1 = xb[(kq*2+1)*33+b];
#pragma unroll
    for (int m = 0; m < NR; ++m) {
      const h2* wp = &wl[m * 512 + c * 64 + kq * 2];
      float a = acc[m];
      a = dot2f(x0, wp[0], a); a = dot2f(x1, wp[1], a);
      acc[m] = a;
    }
    if (c < 7) flush(c + 1);
    __syncthreads();
  }
  // ss: reduce over the 32 staging lanes of each row (within half-wave)
  ssacc += __shfl_xor(ssacc, 16);
  ssacc += __shfl_xor(ssacc, 8);
  ssacc += __shfl_xor(ssacc, 4);
  ssacc += __shfl_xor(ssacc, 2);
  ssacc += __shfl_xor(ssacc, 1);
  if (ln == 0) ssrow[sb] = ssacc;
  // acc: combine kq pairs within wave, then LDS-atomic across 16 waves
#pragma unroll
  for (int m = 0; m < NR; ++m) acc[m] += __shfl_xor(acc[m], 32);
  if ((tid & 63) < 32) {
#pragma unroll
    for (int m = 0; m < NR; ++m) atomicAdd(&red[b * 17 + m], acc[m]);
  }
  __syncthreads();
  float z = 0.f;
  if (tid < 32 * NR) {
    const int b2 = tid / NR, m2 = tid % NR;
    z = red[b2 * 17 + m2];
  }
  return z;
}

// ---- fc2-like stage, 1024-thread version: K-slice 1024, uncached y reads ----
__device__ float fc2like(int tid,
    const unsigned* __restrict__ ysrc,
    const h2* __restrict__ wl, h2* __restrict__ xs, float* __restrict__ red) {
  const int b = tid & 31, kq = tid >> 5;
  const int sb = tid >> 5, ln = tid & 31;
  const int e2 = ln * 2;
  float acc[16];
#pragma unroll
  for (int m = 0; m < 16; ++m) acc[m] = 0.f;
  for (int i = tid; i < 544; i += 1024) red[i] = 0.f;
  unsigned q0, q1;
  auto ldchunk = [&](int c) {
    const unsigned* sp = ysrc + (size_t)sb * (MM / 2) + c * 64 + ln * 2;
    q0 = ldb_u32(sp + 0); q1 = ldb_u32(sp + 1);
  };
  auto flush = [&](int c) {
    h2* dst = xs + (c & 1) * (64 * 33);
    dst[(e2+0)*33+sb] = __builtin_bit_cast(h2, q0);
    dst[(e2+1)*33+sb] = __builtin_bit_cast(h2, q1);
  };
  ldchunk(0); flush(0);
  __syncthreads();
  for (int c = 0; c < 8; ++c) {
    if (c < 7) ldchunk(c + 1);
    const h2* xb = xs + (c & 1) * (64 * 33);
    h2 x0 = xb[(kq*2+0)*33+b], x1 = xb[(kq*2+1)*33+b];
#pragma unroll
    for (int m = 0; m < 16; ++m) {
      const h2* wp = &wl[m * 512 + c * 64 + kq * 2];
      float a = acc[m];
      a = dot2f(x0, wp[0], a); a = dot2f(x1, wp[1], a);
      acc[m] = a;
    }
    if (c < 7) flush(c + 1);
    __syncthreads();
  }
#pragma unroll
  for (int m = 0; m < 16; ++m) acc[m] += __shfl_xor(acc[m], 32);
  if ((tid & 63) < 32) {
#pragma unroll
    for (int m = 0; m < 16; ++m) atomicAdd(&red[b * 17 + m], acc[m]);
  }
  __syncthreads();
  float z = 0.f;
  if (tid < 512) {
    const int b2 = tid >> 4, m2 = tid & 15;
    z = red[b2 * 17 + m2];
  }
  return z;
}

struct Scan4Params {
  const int* tokens; const float* embw;
  const float* bnw; const float* fc1w; const float* fc1b;
  const float* fc2w; const float* fc2b;
  const float* nw; const float* nxtw; const float* nxtb;
  float* inp_all;   // [TT][32][EE] (d_out q3)
  float* s_all;     // [TT][32][EE] (d_out q2)
  float* hbuf_all;  // [TT][32][EE] (d_out q4)
  float* nxt_all;   // [TT][32][EE] (ws)
  unsigned* yh;     // [32][MM/2] fp16 pairs (ws)
  float* ssS;       // [TT][32]
  unsigned* cnt;    // barrier counters
};

__global__ __launch_bounds__(1024, 1) void k_scan4(Scan4Params p) {
  extern __shared__ __align__(16) char smem[];
  h2* w1a = (h2*)smem;                      // [16][512]  32KB
  h2* w1b = (h2*)(smem + 32768);            // 32KB
  h2* w2a = (h2*)(smem + 65536);            // [16][512] K-slice, 32KB
  h2* w2b = (h2*)(smem + 98304);            // 32KB
  h2* wn  = (h2*)(smem + 131072);           // [4][512]   8KB
  h2* xs  = (h2*)(smem + 139264);           // 2x[64][33] h2 = 16896B
  float* red = (float*)(smem + 156160);     // [32][17] f32 = 2176B
  float* ssrow = (float*)(smem + 158336);   // [32] = 128B  (total 158464)
  const int tid = threadIdx.x;
  const int cu = blockIdx.x;
  const int cg = cu & 63, ks = cu >> 6;

  // one-time: stage this block's weight slices fp32 -> fp16 LDS (1024 thr)
#pragma unroll
  for (int j = 0; j < 8; ++j) {
    int idx = tid + j * 1024;               // 0..8191
    int r = idx >> 9, k = idx & 511;
    float2 f = *(const float2*)&p.fc1w[(size_t)(cu * 16 + r) * EE + k * 2];
    h2 h; h[0] = (_Float16)f.x; h[1] = (_Float16)f.y;
    w1a[r * 512 + k] = h;
    float2 g = *(const float2*)&p.fc1w[(size_t)MM * EE +
                                       (size_t)(cu * 16 + r) * EE + k * 2];
    h2 hb; hb[0] = (_Float16)g.x; hb[1] = (_Float16)g.y;
    w1b[r * 512 + k] = hb;
    float2 a = *(const float2*)&p.fc2w[(size_t)(cg * 16 + r) * MM +
                                       ks * 1024 + k * 2];
    h2 ha; ha[0] = (_Float16)a.x; ha[1] = (_Float16)a.y;
    w2a[r * 512 + k] = ha;
    float2 bb = *(const float2*)&p.fc2w[(size_t)EE * MM +
                                        (size_t)(cg * 16 + r) * MM +
                                        ks * 1024 + k * 2];
    h2 hc; hc[0] = (_Float16)bb.x; hc[1] = (_Float16)bb.y;
    w2b[r * 512 + k] = hc;
  }
#pragma unroll
  for (int j = 0; j < 2; ++j) {
    int idx = tid + j * 1024;               // 0..2047
    int r = idx >> 9, k = idx & 511;
    float2 f = *(const float2*)&p.nxtw[(size_t)(cu * 4 + r) * EE + k * 2];
    h2 h; h[0] = (_Float16)f.x; h[1] = (_Float16)f.y;
    wn[r * 512 + k] = h;
  }
  __syncthreads();

  int sidx = 0;
  for (int t = 0; t < TT; ++t) {
    const float* inp = p.inp_all + (size_t)t * BE;
    float* hb = p.hbuf_all + (size_t)t * BE;
    float* st = p.s_all + (size_t)t * BE;

    // A: y0 = silu(rms(inp)@w1a + b); all blocks seed their 4 cols of hbuf
    {
      float z = fc1like<16>(tid, cu, inp, p.bnw, w1a, xs, red, ssrow,
                            hb, nullptr, p.fc2b);
      if (tid < 512) {
        const int b2 = tid >> 4, m2 = tid & 15, gm = cu * 16 + m2;
        float rinv = rsqrtf(ssrow[b2] * (1.f / EE) + EPSF);
        float zz = z * rinv + p.fc1b[gm];
        float yv = zz / (1.f + expf(-zz));
        unsigned bits = (unsigned)__builtin_bit_cast(unsigned short, (_Float16)yv);
        unsigned other = __shfl_xor(bits, 1);
        if ((tid & 1) == 0)
          stb_u32(&p.yh[b2 * (MM / 2) + (gm >> 1)], bits | (other << 16));
      }
    }
    gbar4(p.cnt, sidx++);
    // B: hbuf += y0-slice @ w2a-slice (K-split atomics)
    {
      float z = fc2like(tid, p.yh + ks * 512, w2a, xs, red);
      if (tid < 512)
        atomicAdd(&hb[(tid >> 4) * EE + cg * 16 + (tid & 15)], z);
    }
    gbar4(p.cnt, sidx++);
    // C: y1 = silu(rms(h)@w1b + b); all blocks seed their 4 cols of s
    {
      float z = fc1like<16>(tid, cu, hb, p.bnw + EE, w1b, xs, red, ssrow,
                            st, inp, p.fc2b + EE);
      if (tid < 512) {
        const int b2 = tid >> 4, m2 = tid & 15, gm = cu * 16 + m2;
        float rinv = rsqrtf(ssrow[b2] * (1.f / EE) + EPSF);
        float zz = z * rinv + p.fc1b[MM + gm];
        float yv = zz / (1.f + expf(-zz));
        unsigned bits = (unsigned)__builtin_bit_cast(unsigned short, (_Float16)yv);
        unsigned other = __shfl_xor(bits, 1);
        if ((tid & 1) == 0)
          stb_u32(&p.yh[b2 * (MM / 2) + (gm >> 1)], bits | (other << 16));
      }
    }
    gbar4(p.cnt, sidx++);
    // D: s += y1-slice @ w2b-slice
    {
      float z = fc2like(tid, p.yh + ks * 512, w2b, xs, red);
      if (tid < 512)
        atomicAdd(&st[(tid >> 4) * EE + cg * 16 + (tid & 15)], z);
    }
    gbar4(p.cnt, sidx++);
    // E: nxt = rms(s)@wn + nb; carry inp_{t+1}; persist ssS
    {
      float z = fc1like<4>(tid, cu, st, p.nw, wn, xs, red, ssrow,
                           nullptr, nullptr, nullptr);
      if (cu == 0 && tid < 32) p.ssS[t * 32 + tid] = ssrow[tid];
      if (tid < 128) {
        const int b2 = tid >> 2, m2 = tid & 3, gn = cu * 4 + m2;
        float rinv = rsqrtf(ssrow[b2] * (1.f / EE) + EPSF);
        float nv = z * rinv + p.nxtb[gn];
        stb_f32(&p.nxt_all[(size_t)t * BE + b2 * EE + gn], nv);
        if (t + 1 < TT) {
          int tok = p.tokens[b2 * TT + t + 1];
          stb_f32(&p.inp_all[(size_t)(t + 1) * BE + b2 * EE + gn],
                  p.embw[(size_t)tok * EE + gn] + nv);
        }
      }
    }
    gbar4(p.cnt, sidx++);
  }
}

// ======================= helpers =======================

__global__ void k_zero(float* __restrict__ p, int n) {
  int i = blockIdx.x * 256 + threadIdx.x;
  if (i < n) p[i] = 0.f;
}

__global__ void k_init(const int* __restrict__ tokens,
                       const float* __restrict__ embw,
                       float* __restrict__ inp0) {
  int b = blockIdx.x;
  int tok = tokens[b * TT];
  int e = threadIdx.x * 4;
  float4 v = *(const float4*)&embw[(size_t)tok * EE + e];
  *(float4*)&inp0[b * EE + e] = v;
}

// ======================= legacy fallback (round-1, proven) =======================

__global__ __launch_bounds__(256)
void k_fc1(const float* __restrict__ h, const float* __restrict__ bnw,
           const float* __restrict__ W, const float* __restrict__ bias,
           float* __restrict__ yout, float* __restrict__ initDst,
           const float* __restrict__ initAdd, const float* __restrict__ initBias) {
  __shared__ __align__(16) float Hs[32][68];
  __shared__ __align__(16) float Ws[8][68];
  __shared__ float ssrow[32];
  const int tid = threadIdx.x;
  const int col0 = blockIdx.x * 8;
  const int c = tid & 7;
  const int b = tid >> 3;
  const bool writer = (blockIdx.x == 0);
  float acc = 0.f;
  float ssl[8];
#pragma unroll
  for (int j = 0; j < 8; ++j) ssl[j] = 0.f;
  for (int kc = 0; kc < EE; kc += 64) {
#pragma unroll
    for (int j = 0; j < 8; ++j) {
      int i = tid + j * 256;
      int bb = i >> 6, k = i & 63;
      float v = h[bb * EE + kc + k];
      ssl[j] += v * v;
      Hs[bb][k] = v * bnw[kc + k];
      if (writer) {
        float d = v + initBias[kc + k];
        if (initAdd) d += initAdd[bb * EE + kc + k];
        initDst[bb * EE + kc + k] = d;
      }
    }
#pragma unroll
    for (int j = 0; j < 2; ++j) {
      int i = tid + j * 256;
      int cc = i >> 6, k = i & 63;
      Ws[cc][k] = W[(size_t)(col0 + cc) * EE + kc + k];
    }
    __syncthreads();
#pragma unroll
    for (int k = 0; k < 64; k += 4) {
      float4 w4 = *(const float4*)&Ws[c][k];
      float4 h4 = *(const float4*)&Hs[b][k];
      acc += h4.x * w4.x + h4.y * w4.y + h4.z * w4.z + h4.w * w4.w;
    }
    __syncthreads();
  }
  const int wv = tid >> 6;
#pragma unroll
  for (int j = 0; j < 8; ++j) {
    float v = ssl[j];
#pragma unroll
    for (int off = 32; off > 0; off >>= 1) v += __shfl_xor(v, off);
    if ((tid & 63) == 0) ssrow[wv + 4 * j] = v;
  }
  __syncthreads();
  float rinv = rsqrtf(ssrow[b] * (1.f / EE) + EPSF);
  float z = acc * rinv + bias[col0 + c];
  yout[b * MM + col0 + c] = z / (1.f + expf(-z));
}

__global__ __launch_bounds__(256)
void k_fc2(const float* __restrict__ y, const float* __restrict__ W2,
           float* __restrict__ dest) {
  __shared__ __align__(16) float Ys[32][68];
  __shared__ __align__(16) float Ws[16][68];
  const int tid = threadIdx.x;
  const int cgi = blockIdx.x & 63;
  const int ks = blockIdx.x >> 6;
  const int col0 = cgi * 16;
  const int c = tid & 15;
  const int bq = tid >> 4;
  float acc0 = 0.f, acc1 = 0.f;
  const int kend = ks * 512 + 512;
  for (int kc = ks * 512; kc < kend; kc += 64) {
#pragma unroll
    for (int j = 0; j < 8; ++j) {
      int i = tid + j * 256;
      int bb = i >> 6, k = i & 63;
      Ys[bb][k] = y[bb * MM + kc + k];
    }
#pragma unroll
    for (int j = 0; j < 4; ++j) {
      int i = tid + j * 256;
      int cc = i >> 6, k = i & 63;
      Ws[cc][k] = W2[(size_t)(col0 + cc) * MM + kc + k];
    }
    __syncthreads();
#pragma unroll
    for (int k = 0; k < 64; k += 4) {
      float4 w4 = *(const float4*)&Ws[c][k];
      float4 a4 = *(const float4*)&Ys[bq][k];
      float4 b4 = *(const float4*)&Ys[bq + 16][k];
      acc0 += a4.x * w4.x + a4.y * w4.y + a4.z * w4.z + a4.w * w4.w;
      acc1 += b4.x * w4.x + b4.y * w4.y + b4.z * w4.z + b4.w * w4.w;
    }
    __syncthreads();
  }
  atomicAdd(&dest[bq * EE + col0 + c], acc0);
  atomicAdd(&dest[(bq + 16) * EE + col0 + c], acc1);
}

__global__ __launch_bounds__(256)
void k_nxt(const float* __restrict__ s, const float* __restrict__ nw,
           const float* __restrict__ Wn, const float* __restrict__ nb,
           float* __restrict__ nxt_out, float* __restrict__ ss_out,
           const int* __restrict__ tokens, const float* __restrict__ embw,
           float* __restrict__ inp_next, int tnext) {
  __shared__ __align__(16) float Xs[32][68];
  __shared__ __align__(16) float Ws[8][68];
  __shared__ float ssrow[32];
  const int tid = threadIdx.x;
  const int col0 = blockIdx.x * 8;
  const int c = tid & 7;
  const int b = tid >> 3;
  float acc = 0.f;
  float ssl[8];
#pragma unroll
  for (int j = 0; j < 8; ++j) ssl[j] = 0.f;
  for (int kc = 0; kc < EE; kc += 64) {
#pragma unroll
    for (int j = 0; j < 8; ++j) {
      int i = tid + j * 256;
      int bb = i >> 6, k = i & 63;
      float v = s[bb * EE + kc + k];
      ssl[j] += v * v;
      Xs[bb][k] = v * nw[kc + k];
    }
#pragma unroll
    for (int j = 0; j < 2; ++j) {
      int i = tid + j * 256;
      int cc = i >> 6, k = i & 63;
      Ws[cc][k] = Wn[(size_t)(col0 + cc) * EE + kc + k];
    }
    __syncthreads();
#pragma unroll
    for (int k = 0; k < 64; k += 4) {
      float4 w4 = *(const float4*)&Ws[c][k];
      float4 h4 = *(const float4*)&Xs[b][k];
      acc += h4.x * w4.x + h4.y * w4.y + h4.z * w4.z + h4.w * w4.w;
    }
    __syncthreads();
  }
  const int wv = tid >> 6;
#pragma unroll
  for (int j = 0; j < 8; ++j) {
    float v = ssl[j];
#pragma unroll
    for (int off = 32; off > 0; off >>= 1) v += __shfl_xor(v, off);
    if ((tid & 63) == 0) {
      ssrow[wv + 4 * j] = v;
      if (blockIdx.x == 0) ss_out[wv + 4 * j] = v;
    }
  }
  __syncthreads();
  float rinv = rsqrtf(ssrow[b] * (1.f / EE) + EPSF);
  float nv = acc * rinv + nb[col0 + c];
  nxt_out[b * EE + col0 + c] = nv;
  if (inp_next) {
    int tok = tokens[b * TT + tnext];
    inp_next[b * EE + col0 + c] = embw[(size_t)tok * EE + col0 + c] + nv;
  }
}

// ======================= phase 2 (fp16 dot2) =======================

__global__ __launch_bounds__(256)
void k_curemb(const float* __restrict__ s_all, const float* __restrict__ ss_s,
              const float* __restrict__ nw, const float* __restrict__ Wc,
              const float* __restrict__ cb, const float* __restrict__ inp_all,
              float* __restrict__ cur_out, float* __restrict__ aux_accum) {
  __shared__ __align__(16) h2 Ah[8 * 68];
  __shared__ __align__(16) h2 Bh[8 * 68];
  __shared__ float rr[64];
  __shared__ float wred[4];
  const int tid = threadIdx.x;
  const int rt = blockIdx.x & 127;
  const int ct = blockIdx.x >> 7;
  const int row0 = rt * 64, col0 = ct * 64;
  if (tid < 64) rr[tid] = rsqrtf(ss_s[row0 + tid] * (1.f / EE) + EPSF);
  __syncthreads();
  float acc[4][4];
#pragma unroll
  for (int i = 0; i < 4; ++i)
#pragma unroll
    for (int j = 0; j < 4; ++j) acc[i][j] = 0.f;
  const int tx = tid & 15, ty = tid >> 4;
  for (int kc = 0; kc < EE; kc += 16) {
#pragma unroll
    for (int j = 0; j < 2; ++j) {
      int idx = tid + j * 256;           // 0..511
      int kp = idx & 7, m = idx >> 3;    // m 0..63
      float2 f = *(const float2*)&s_all[(size_t)(row0 + m) * EE + kc + 2 * kp];
      float2 n2 = *(const float2*)&nw[kc + 2 * kp];
      float r = rr[m];
      h2 hv; hv[0] = (_Float16)(f.x * r * n2.x); hv[1] = (_Float16)(f.y * r * n2.y);
      Ah[kp * 68 + m] = hv;
      float2 w2 = *(const float2*)&Wc[(size_t)(col0 + m) * EE + kc + 2 * kp];
      h2 hw; hw[0] = (_Float16)w2.x; hw[1] = (_Float16)w2.y;
      Bh[kp * 68 + m] = hw;
    }
    __syncthreads();
#pragma unroll
    for (int kp = 0; kp < 8; ++kp) {
      h2 a0 = Ah[kp*68 + tx*4 + 0], a1 = Ah[kp*68 + tx*4 + 1];
      h2 a2 = Ah[kp*68 + tx*4 + 2], a3 = Ah[kp*68 + tx*4 + 3];
      h2 b0 = Bh[kp*68 + ty*4 + 0], b1 = Bh[kp*68 + ty*4 + 1];
      h2 b2 = Bh[kp*68 + ty*4 + 2], b3 = Bh[kp*68 + ty*4 + 3];
      acc[0][0]=dot2f(a0,b0,acc[0][0]); acc[0][1]=dot2f(a0,b1,acc[0][1]);
      acc[0][2]=dot2f(a0,b2,acc[0][2]); acc[0][3]=dot2f(a0,b3,acc[0][3]);
      acc[1][0]=dot2f(a1,b0,acc[1][0]); acc[1][1]=dot2f(a1,b1,acc[1][1]);
      acc[1][2]=dot2f(a1,b2,acc[1][2]); acc[1][3]=dot2f(a1,b3,acc[1][3]);
      acc[2][0]=dot2f(a2,b0,acc[2][0]); acc[2][1]=dot2f(a2,b1,acc[2][1]);
      acc[2][2]=dot2f(a2,b2,acc[2][2]); acc[2][3]=dot2f(a2,b3,acc[2][3]);
      acc[3][0]=dot2f(a3,b0,acc[3][0]); acc[3][1]=dot2f(a3,b1,acc[3][1]);
      acc[3][2]=dot2f(a3,b2,acc[3][2]); acc[3][3]=dot2f(a3,b3,acc[3][3]);
    }
    __syncthreads();
  }
  float auxp = 0.f;
#pragma unroll
  for (int i = 0; i < 4; ++i) {
    int r = row0 + tx * 4 + i;
#pragma unroll
    for (int j = 0; j < 4; ++j) {
      int col = col0 + ty * 4 + j;
      float v = acc[i][j] + cb[col];
      cur_out[(size_t)r * EE + col] = v;
      float d = v - inp_all[(size_t)r * EE + col];
      auxp += d * d;
    }
  }
#pragma unroll
  for (int off = 32; off > 0; off >>= 1) auxp += __shfl_xor(auxp, off);
  if ((tid & 63) == 0) wred[tid >> 6] = auxp;
  __syncthreads();
  if (tid == 0) atomicAdd(aux_accum, wred[0] + wred[1] + wred[2] + wred[3]);
}

__global__ __launch_bounds__(256)
void k_logits(const float* __restrict__ A, const float* __restrict__ embw,
              const int* __restrict__ idxs, float* __restrict__ rowsum,
              float* __restrict__ lidx, float* __restrict__ store) {
  __shared__ __align__(16) h2 Ah[8 * 68];
  __shared__ __align__(16) h2 Bh[8 * 68];
  __shared__ float rowpart[64];
  const int tid = threadIdx.x;
  const int rt = blockIdx.x & 127;
  const int ct = blockIdx.x >> 7;
  const int row0 = rt * 64, col0 = ct * 64;
  float acc[4][4];
#pragma unroll
  for (int i = 0; i < 4; ++i)
#pragma unroll
    for (int j = 0; j < 4; ++j) acc[i][j] = 0.f;
  const int tx = tid & 15, ty = tid >> 4;
  for (int kc = 0; kc < EE; kc += 16) {
#pragma unroll
    for (int j = 0; j < 2; ++j) {
      int idx = tid + j * 256;
      int kp = idx & 7, m = idx >> 3;
      float2 f = *(const float2*)&A[(size_t)(row0 + m) * EE + kc + 2 * kp];
      h2 hv; hv[0] = (_Float16)f.x; hv[1] = (_Float16)f.y;
      Ah[kp * 68 + m] = hv;
      float2 w2 = *(const float2*)&embw[(size_t)(col0 + m) * EE + kc + 2 * kp];
      h2 hw; hw[0] = (_Float16)w2.x; hw[1] = (_Float16)w2.y;
      Bh[kp * 68 + m] = hw;
    }
    __syncthreads();
#pragma unroll
    for (int kp = 0; kp < 8; ++kp) {
      h2 a0 = Ah[kp*68 + tx*4 + 0], a1 = Ah[kp*68 + tx*4 + 1];
      h2 a2 = Ah[kp*68 + tx*4 + 2], a3 = Ah[kp*68 + tx*4 + 3];
      h2 b0 = Bh[kp*68 + ty*4 + 0], b1 = Bh[kp*68 + ty*4 + 1];
      h2 b2 = Bh[kp*68 + ty*4 + 2], b3 = Bh[kp*68 + ty*4 + 3];
      acc[0][0]=dot2f(a0,b0,acc[0][0]); acc[0][1]=dot2f(a0,b1,acc[0][1]);
      acc[0][2]=dot2f(a0,b2,acc[0][2]); acc[0][3]=dot2f(a0,b3,acc[0][3]);
      acc[1][0]=dot2f(a1,b0,acc[1][0]); acc[1][1]=dot2f(a1,b1,acc[1][1]);
      acc[1][2]=dot2f(a1,b2,acc[1][2]); acc[1][3]=dot2f(a1,b3,acc[1][3]);
      acc[2][0]=dot2f(a2,b0,acc[2][0]); acc[2][1]=dot2f(a2,b1,acc[2][1]);
      acc[2][2]=dot2f(a2,b2,acc[2][2]); acc[2][3]=dot2f(a2,b3,acc[2][3]);
      acc[3][0]=dot2f(a3,b0,acc[3][0]); acc[3][1]=dot2f(a3,b1,acc[3][1]);
      acc[3][2]=dot2f(a3,b2,acc[3][2]); acc[3][3]=dot2f(a3,b3,acc[3][3]);
    }
    __syncthreads();
  }
  if (tid < 64) rowpart[tid] = 0.f;
  __syncthreads();
#pragma unroll
  for (int i = 0; i < 4; ++i) {
    int r = row0 + tx * 4 + i;
    int t = r >> 5, bb = r & 31;
    int idx = idxs[bb * TT + t];
    float e0 = expf(acc[i][0]);
    float e1 = expf(acc[i][1]);
    float e2 = expf(acc[i][2]);
    float e3 = expf(acc[i][3]);
    atomicAdd(&rowpart[tx * 4 + i], e0 + e1 + e2 + e3);
    int cbase = col0 + ty * 4;
#pragma unroll
    for (int j = 0; j < 4; ++j)
      if (cbase + j == idx) lidx[r] = acc[i][j];
    if (store) {
      float4 o = make_float4(acc[i][0], acc[i][1], acc[i][2], acc[i][3]);
      *(float4*)(store + ((size_t)bb * TT + t) * VV + cbase) = o;
    }
  }
  __syncthreads();
  if (tid < 64) atomicAdd(&rowsum[row0 + tid], rowpart[tid]);
}

__global__ void k_final(const float* __restrict__ rs_cur,
                        const float* __restrict__ rs_nxt,
                        const float* __restrict__ ltok,
                        const float* __restrict__ ltgt,
                        const float* __restrict__ aux_accum,
                        float* __restrict__ out) {
  float p = 0.f;
  for (int r = threadIdx.x; r < NROWS; r += 256)
    p += (ltok[r] - logf(rs_cur[r])) + (ltgt[r] - logf(rs_nxt[r]));
#pragma unroll
  for (int off = 32; off > 0; off >>= 1) p += __shfl_xor(p, off);
  __shared__ float w[4];
  if ((threadIdx.x & 63) == 0) w[threadIdx.x >> 6] = p;
  __syncthreads();
  if (threadIdx.x == 0) {
    float tot = w[0] + w[1] + w[2] + w[3];
    out[0] = -tot / (2.f * (float)NROWS);
    out[1] = aux_accum[0] * (1.f / ((float)NROWS * EE));
  }
}

// ======================= launch =======================

extern "C" void kernel_launch(void* const* d_in, const int* in_sizes, int n_in,
                              void* d_out, int out_size, void* d_ws, size_t ws_size,
                              hipStream_t stream) {
  (void)in_sizes; (void)n_in; (void)out_size; (void)ws_size;
  const int*   tokens  = (const int*)d_in[0];
  const int*   targets = (const int*)d_in[1];
  const float* embw    = (const float*)d_in[2];
  const float* bnw     = (const float*)d_in[3];
  const float* fc1w    = (const float*)d_in[4];
  const float* fc1b    = (const float*)d_in[5];
  const float* fc2w    = (const float*)d_in[6];
  const float* fc2b    = (const float*)d_in[7];
  const float* nw      = (const float*)d_in[8];
  const float* curw    = (const float*)d_in[9];
  const float* curb    = (const float*)d_in[10];
  const float* nxtw    = (const float*)d_in[11];
  const float* nxtb    = (const float*)d_in[12];
  float* out = (float*)d_out;

  // d_out quadrants (each 8,388,608 floats); all overwritten by final k_logits
  float* cur_all  = out;
  float* s_all    = out + (size_t)NROWS * EE;
  float* inp_all  = out + 2 * (size_t)NROWS * EE;
  float* hbuf_all = out + 3 * (size_t)NROWS * EE;

  float* ws       = (float*)d_ws;
  float* nxt_all  = ws;                       // 8,388,608
  float* ltok     = ws + 8388608;             // 8,192
  float* ltgt     = ws + 8396800;             // 8,192
  unsigned* yh    = (unsigned*)(ws + 8404992);// 65,536 u32
  float* rs_cur   = ws + 8470528;             // 8,192
  float* rs_nxt   = ws + 8478720;             // 8,192
  float* auxac    = ws + 8486912;             // 1 (+pad)
  unsigned* cnt   = (unsigned*)(ws + 8486944);// 1280*17*32 = 696,320
  float* ssS      = ws + 9183264;             // 8,192
  float* ybuf     = ws + 9191456;             // 131,072 (fallback)

  // zero rs_cur..auxac+pad + counters (contiguous span)
  const int nzero = (8486944 + 696320) - 8470528;
  k_zero<<<(nzero + 255) / 256, 256, 0, stream>>>(rs_cur, nzero);
  k_init<<<32, 256, 0, stream>>>(tokens, embw, inp_all);

  Scan4Params p;
  p.tokens = tokens; p.embw = embw; p.bnw = bnw;
  p.fc1w = fc1w; p.fc1b = fc1b; p.fc2w = fc2w; p.fc2b = fc2b;
  p.nw = nw; p.nxtw = nxtw; p.nxtb = nxtb;
  p.inp_all = inp_all; p.s_all = s_all; p.hbuf_all = hbuf_all;
  p.nxt_all = nxt_all; p.yh = yh; p.ssS = ssS; p.cnt = cnt;

  const size_t shmem = 158464;
  hipError_t err = hipFuncSetAttribute((const void*)k_scan4,
      hipFuncAttributeMaxDynamicSharedMemorySize, (int)shmem);
  if (err == hipSuccess) {
    void* args[] = { &p };
    err = hipLaunchCooperativeKernel((const void*)k_scan4, dim3(256), dim3(1024),
                                     args, shmem, stream);
  }
  if (err != hipSuccess) {
    // fallback: proven round-1 multi-kernel sequence (fp32)
    float* hbuf = hbuf_all;  // single reused buffer
    for (int t = 0; t < TT; ++t) {
      const float* inp = inp_all + (size_t)t * BE;
      float* s = s_all + (size_t)t * BE;
      k_fc1<<<512, 256, 0, stream>>>(inp, bnw, fc1w, fc1b, ybuf,
                                     hbuf, nullptr, fc2b);
      k_fc2<<<512, 256, 0, stream>>>(ybuf, fc2w, hbuf);
      k_fc1<<<512, 256, 0, stream>>>(hbuf, bnw + EE, fc1w + (size_t)MM * EE,
                                     fc1b + MM, ybuf, s, inp, fc2b + EE);
      k_fc2<<<512, 256, 0, stream>>>(ybuf, fc2w + (size_t)EE * MM, s);
      k_nxt<<<128, 256, 0, stream>>>(s, nw, nxtw, nxtb,
                                     nxt_all + (size_t)t * BE, ssS + t * BB,
                                     tokens, embw,
                                     (t + 1 < TT) ? inp_all + (size_t)(t + 1) * BE : nullptr,
                                     t + 1);
    }
  }

  k_curemb<<<2048, 256, 0, stream>>>(s_all, ssS, nw, curw, curb, inp_all,
                                     cur_all, auxac);
  k_logits<<<8192, 256, 0, stream>>>(cur_all, embw, tokens, rs_cur, ltok, nullptr);
  k_logits<<<8192, 256, 0, stream>>>(nxt_all, embw, targets, rs_nxt, ltgt, out);
  k_final<<<1, 256, 0, stream>>>(rs_cur, rs_nxt, ltok, ltgt, auxac,
                                 out + (size_t)NROWS * VV);
}

// Round 15
// 17333.372 us; speedup vs baseline: 2.6737x; 2.6737x over previous
//
#include <hip/hip_runtime.h>
#include <math.h>

#define TT  256
#define BB  32
#define EE  1024
#define MM  4096
#define VV  4096
#define BE  (BB*EE)
#define NROWS (TT*BB)
#define EPSF 1.1920929e-07f

typedef _Float16 h2 __attribute__((ext_vector_type(2)));

__device__ inline float dot2f(h2 a, h2 b, float c) {
#if __has_builtin(__builtin_amdgcn_fdot2)
  return __builtin_amdgcn_fdot2(a, b, c, false);
#else
  return c + (float)a[0] * (float)b[0] + (float)a[1] * (float)b[1];
#endif
}

// ---- coherent-point (MALL) data movement: relaxed agent atomics = cache bypass ----
__device__ inline unsigned ldb_u32(const unsigned* p) {
  return __hip_atomic_load((unsigned*)p, __ATOMIC_RELAXED, __HIP_MEMORY_SCOPE_AGENT);
}
__device__ inline void stb_u32(unsigned* p, unsigned v) {
  __hip_atomic_store(p, v, __ATOMIC_RELAXED, __HIP_MEMORY_SCOPE_AGENT);
}
__device__ inline void stb_f32(float* p, float v) {
  __hip_atomic_store(p, v, __ATOMIC_RELAXED, __HIP_MEMORY_SCOPE_AGENT);
}

// ---- fence-free hierarchical grid barrier (fresh counters per barrier) ----
// Safe without fences: __syncthreads drains vmcnt(0) (all cross-block stores
// complete at MALL: stb/atomics), then relaxed arrive; consumers' cached reads
// are first-touch per-t addresses (or uncached for reused yh).
__device__ inline void gbar4(unsigned* cnt, int sidx) {
  __syncthreads();
  if (threadIdx.x == 0) {
    unsigned* base = cnt + (size_t)sidx * 17 * 32;
    unsigned* gp = base + (blockIdx.x & 15) * 32;
    unsigned* mp = base + 16 * 32;
    unsigned old = __hip_atomic_fetch_add(gp, 1u, __ATOMIC_RELAXED,
                                          __HIP_MEMORY_SCOPE_AGENT);
    if (old == 15u)
      __hip_atomic_fetch_add(mp, 1u, __ATOMIC_RELAXED, __HIP_MEMORY_SCOPE_AGENT);
    while (__hip_atomic_load(mp, __ATOMIC_RELAXED, __HIP_MEMORY_SCOPE_AGENT) < 16u)
      __builtin_amdgcn_s_sleep(1);
  }
  __syncthreads();
}

// ---- fc1-like stage (R12-proven body): LDS-staged, 1-deep chunk prefetch ----
// DISTRIBUTED seeding: block cu seeds exactly cols [4cu, 4cu+4) from registers
// it already holds (chunk cu>>5, staging thread (tid&15)==((cu&31)>>1), half
// (cu&1)*4).
template<int NR>
__device__ float fc1like(int tid, int cu,
    const float* __restrict__ src, const float* __restrict__ scl,
    const h2* __restrict__ wl, h2* __restrict__ xs, float* __restrict__ red,
    float* __restrict__ ssrow,
    float* __restrict__ seedDst, const float* __restrict__ seedAdd,
    const float* __restrict__ seedBias) {
  const int b = tid & 31, kq = tid >> 5;
  const int sb = tid >> 4, se = (tid & 15) * 8;
  const int ep0 = (tid & 15) * 4;
  float ssacc = 0.f;
  float acc[NR];
#pragma unroll
  for (int m = 0; m < NR; ++m) acc[m] = 0.f;
  const int seedChunk = cu >> 5;
  const int seedOff = (cu & 1) * 4;
  const bool seeder = (seedDst != nullptr) && ((tid & 15) == ((cu & 31) >> 1));

  float4 v0, v1, c0v, c1v;
  auto ldchunk = [&](int c) {
    v0 = *(const float4*)&src[sb * EE + c * 128 + se];
    v1 = *(const float4*)&src[sb * EE + c * 128 + se + 4];
    c0v = *(const float4*)&scl[c * 128 + se];
    c1v = *(const float4*)&scl[c * 128 + se + 4];
  };
  auto flush = [&](int c) {
    h2* dst = xs + (c & 1) * (64 * 33);
    ssacc += v0.x*v0.x + v0.y*v0.y + v0.z*v0.z + v0.w*v0.w
           + v1.x*v1.x + v1.y*v1.y + v1.z*v1.z + v1.w*v1.w;
    h2 p0, p1, p2, p3;
    p0[0]=(_Float16)(v0.x*c0v.x); p0[1]=(_Float16)(v0.y*c0v.y);
    p1[0]=(_Float16)(v0.z*c0v.z); p1[1]=(_Float16)(v0.w*c0v.w);
    p2[0]=(_Float16)(v1.x*c1v.x); p2[1]=(_Float16)(v1.y*c1v.y);
    p3[0]=(_Float16)(v1.z*c1v.z); p3[1]=(_Float16)(v1.w*c1v.w);
    dst[(ep0+0)*33+sb]=p0; dst[(ep0+1)*33+sb]=p1;
    dst[(ep0+2)*33+sb]=p2; dst[(ep0+3)*33+sb]=p3;
    if (seeder && c == seedChunk) {
      const int e0 = c * 128 + se + seedOff;
      float a0, a1, a2, a3;
      if (seedOff == 0) { a0 = v0.x; a1 = v0.y; a2 = v0.z; a3 = v0.w; }
      else              { a0 = v1.x; a1 = v1.y; a2 = v1.z; a3 = v1.w; }
      float d0 = a0 + seedBias[e0 + 0];
      float d1 = a1 + seedBias[e0 + 1];
      float d2 = a2 + seedBias[e0 + 2];
      float d3 = a3 + seedBias[e0 + 3];
      if (seedAdd) {
        d0 += seedAdd[sb * EE + e0 + 0];
        d1 += seedAdd[sb * EE + e0 + 1];
        d2 += seedAdd[sb * EE + e0 + 2];
        d3 += seedAdd[sb * EE + e0 + 3];
      }
      stb_f32(&seedDst[sb * EE + e0 + 0], d0);
      stb_f32(&seedDst[sb * EE + e0 + 1], d1);
      stb_f32(&seedDst[sb * EE + e0 + 2], d2);
      stb_f32(&seedDst[sb * EE + e0 + 3], d3);
    }
  };
  ldchunk(0); flush(0);
  __syncthreads();
  for (int c = 0; c < 8; ++c) {
    if (c < 7) ldchunk(c + 1);
    const h2* xb = xs + (c & 1) * (64 * 33);
    h2 x0 = xb[(kq*4+0)*33+b], x1 = xb[(kq*4+1)*33+b],
       x2 = xb[(kq*4+2)*33+b], x3 = xb[(kq*4+3)*33+b];
#pragma unroll
    for (int m = 0; m < NR; ++m) {
      const h2* wp = &wl[m * 512 + c * 64 + kq * 4];
      float a = acc[m];
      a = dot2f(x0, wp[0], a); a = dot2f(x1, wp[1], a);
      a = dot2f(x2, wp[2], a); a = dot2f(x3, wp[3], a);
      acc[m] = a;
    }
    if (c < 7) flush(c + 1);
    __syncthreads();
  }
  ssacc += __shfl_xor(ssacc, 8);
  ssacc += __shfl_xor(ssacc, 4);
  ssacc += __shfl_xor(ssacc, 2);
  ssacc += __shfl_xor(ssacc, 1);
  if ((tid & 15) == 0) ssrow[sb] = ssacc;
#pragma unroll
  for (int m = 0; m < NR; ++m) acc[m] += __shfl_xor(acc[m], 32);
  const int wv = tid >> 6, ln = tid & 63;
  if (ln < 32) {
#pragma unroll
    for (int m = 0; m < NR; ++m) red[wv * 544 + ln * 17 + m] = acc[m];
  }
  __syncthreads();
  float z = 0.f;
  if (tid < 32 * NR) {
    const int b2 = (NR == 16) ? (tid >> 4) : (tid >> 2);
    const int m2 = tid & (NR - 1);
#pragma unroll
    for (int w = 0; w < 8; ++w) z += red[w * 544 + b2 * 17 + m2];
  }
  return z;
}

// ---- fc2-like stage (R12-proven body): K-slice 1024; y read via sc1 bypass ----
__device__ float fc2like(int tid,
    const unsigned* __restrict__ ysrc,
    const h2* __restrict__ wl, h2* __restrict__ xs, float* __restrict__ red) {
  const int b = tid & 31, kq = tid >> 5;
  const int sb = tid >> 4;
  const int ep0 = (tid & 15) * 4;
  float acc[16];
#pragma unroll
  for (int m = 0; m < 16; ++m) acc[m] = 0.f;
  unsigned q0, q1, q2, q3;
  auto ldchunk = [&](int c) {
    const unsigned* sp = ysrc + (size_t)sb * (MM / 2) + c * 64 + ep0;
    q0 = ldb_u32(sp + 0); q1 = ldb_u32(sp + 1);
    q2 = ldb_u32(sp + 2); q3 = ldb_u32(sp + 3);
  };
  auto flush = [&](int c) {
    h2* dst = xs + (c & 1) * (64 * 33);
    dst[(ep0+0)*33+sb] = __builtin_bit_cast(h2, q0);
    dst[(ep0+1)*33+sb] = __builtin_bit_cast(h2, q1);
    dst[(ep0+2)*33+sb] = __builtin_bit_cast(h2, q2);
    dst[(ep0+3)*33+sb] = __builtin_bit_cast(h2, q3);
  };
  ldchunk(0); flush(0);
  __syncthreads();
  for (int c = 0; c < 8; ++c) {
    if (c < 7) ldchunk(c + 1);
    const h2* xb = xs + (c & 1) * (64 * 33);
    h2 x0 = xb[(kq*4+0)*33+b], x1 = xb[(kq*4+1)*33+b],
       x2 = xb[(kq*4+2)*33+b], x3 = xb[(kq*4+3)*33+b];
#pragma unroll
    for (int m = 0; m < 16; ++m) {
      const h2* wp = &wl[m * 512 + c * 64 + kq * 4];
      float a = acc[m];
      a = dot2f(x0, wp[0], a); a = dot2f(x1, wp[1], a);
      a = dot2f(x2, wp[2], a); a = dot2f(x3, wp[3], a);
      acc[m] = a;
    }
    if (c < 7) flush(c + 1);
    __syncthreads();
  }
#pragma unroll
  for (int m = 0; m < 16; ++m) acc[m] += __shfl_xor(acc[m], 32);
  const int wv = tid >> 6, ln = tid & 63;
  if (ln < 32) {
#pragma unroll
    for (int m = 0; m < 16; ++m) red[wv * 544 + ln * 17 + m] = acc[m];
  }
  __syncthreads();
  const int b2 = tid >> 4, m2 = tid & 15;
  float z = 0.f;
#pragma unroll
  for (int w = 0; w < 8; ++w) z += red[w * 544 + b2 * 17 + m2];
  return z;
}

struct Scan4Params {
  const int* tokens; const float* embw;
  const float* bnw; const float* fc1w; const float* fc1b;
  const float* fc2w; const float* fc2b;
  const float* nw; const float* nxtw; const float* nxtb;
  float* inp_all;   // [TT][32][EE] (d_out q3)
  float* s_all;     // [TT][32][EE] (d_out q2)
  float* hbuf_all;  // [TT][32][EE] (d_out q4)
  float* nxt_all;   // [TT][32][EE] (ws)
  unsigned* yh;     // [32][MM/2] fp16 pairs (ws)
  float* ssS;       // [TT][32]
  unsigned* cnt;    // barrier counters
};

__global__ __launch_bounds__(512, 1) void k_scan4(Scan4Params p) {
  extern __shared__ __align__(16) char smem[];
  h2* w1a = (h2*)smem;                      // [16][512]
  h2* w1b = (h2*)(smem + 32768);
  h2* w2a = (h2*)(smem + 65536);            // [16][512] K-slice
  h2* w2b = (h2*)(smem + 98304);
  h2* wn  = (h2*)(smem + 131072);           // [4][512]
  h2* xs  = (h2*)(smem + 139264);           // 2x[64][33] h2 (union w/ red)
  float* red = (float*)(smem + 139264);     // [8][32][17] f32
  float* ssrow = (float*)(smem + 156672);   // [32]
  const int tid = threadIdx.x;
  const int cu = blockIdx.x;
  const int cg = cu & 63, ks = cu >> 6;

  // one-time: stage this block's weight slices fp32 -> fp16 LDS
#pragma unroll 4
  for (int r = 0; r < 16; ++r) {
    float2 f = *(const float2*)&p.fc1w[(size_t)(cu * 16 + r) * EE + tid * 2];
    h2 h; h[0] = (_Float16)f.x; h[1] = (_Float16)f.y;
    w1a[r * 512 + tid] = h;
    float2 g = *(const float2*)&p.fc1w[(size_t)MM * EE +
                                       (size_t)(cu * 16 + r) * EE + tid * 2];
    h2 hb; hb[0] = (_Float16)g.x; hb[1] = (_Float16)g.y;
    w1b[r * 512 + tid] = hb;
    float2 a = *(const float2*)&p.fc2w[(size_t)(cg * 16 + r) * MM +
                                       ks * 1024 + tid * 2];
    h2 ha; ha[0] = (_Float16)a.x; ha[1] = (_Float16)a.y;
    w2a[r * 512 + tid] = ha;
    float2 bb = *(const float2*)&p.fc2w[(size_t)EE * MM +
                                        (size_t)(cg * 16 + r) * MM +
                                        ks * 1024 + tid * 2];
    h2 hc; hc[0] = (_Float16)bb.x; hc[1] = (_Float16)bb.y;
    w2b[r * 512 + tid] = hc;
  }
#pragma unroll
  for (int r = 0; r < 4; ++r) {
    float2 f = *(const float2*)&p.nxtw[(size_t)(cu * 4 + r) * EE + tid * 2];
    h2 h; h[0] = (_Float16)f.x; h[1] = (_Float16)f.y;
    wn[r * 512 + tid] = h;
  }
  __syncthreads();

  int sidx = 0;
  for (int t = 0; t < TT; ++t) {
    const float* inp = p.inp_all + (size_t)t * BE;
    float* hb = p.hbuf_all + (size_t)t * BE;
    float* st = p.s_all + (size_t)t * BE;

    // A: y0 = silu(rms(inp)@w1a + b); all blocks seed their 4 cols of hbuf
    {
      float z = fc1like<16>(tid, cu, inp, p.bnw, w1a, xs, red, ssrow,
                            hb, nullptr, p.fc2b);
      const int b2 = tid >> 4, m2 = tid & 15, gm = cu * 16 + m2;
      float rinv = rsqrtf(ssrow[b2] * (1.f / EE) + EPSF);
      float zz = z * rinv + p.fc1b[gm];
      float yv = zz / (1.f + expf(-zz));
      unsigned bits = (unsigned)__builtin_bit_cast(unsigned short, (_Float16)yv);
      unsigned other = __shfl_xor(bits, 1);
      if ((tid & 1) == 0)
        stb_u32(&p.yh[b2 * (MM / 2) + (gm >> 1)], bits | (other << 16));
    }
    gbar4(p.cnt, sidx++);
    // B: hbuf += y0-slice @ w2a-slice (K-split atomics)
    {
      float z = fc2like(tid, p.yh + ks * 512, w2a, xs, red);
      atomicAdd(&hb[(tid >> 4) * EE + cg * 16 + (tid & 15)], z);
    }
    gbar4(p.cnt, sidx++);
    // C: y1 = silu(rms(h)@w1b + b); all blocks seed their 4 cols of s
    {
      float z = fc1like<16>(tid, cu, hb, p.bnw + EE, w1b, xs, red, ssrow,
                            st, inp, p.fc2b + EE);
      const int b2 = tid >> 4, m2 = tid & 15, gm = cu * 16 + m2;
      float rinv = rsqrtf(ssrow[b2] * (1.f / EE) + EPSF);
      float zz = z * rinv + p.fc1b[MM + gm];
      float yv = zz / (1.f + expf(-zz));
      unsigned bits = (unsigned)__builtin_bit_cast(unsigned short, (_Float16)yv);
      unsigned other = __shfl_xor(bits, 1);
      if ((tid & 1) == 0)
        stb_u32(&p.yh[b2 * (MM / 2) + (gm >> 1)], bits | (other << 16));
    }
    gbar4(p.cnt, sidx++);
    // D: s += y1-slice @ w2b-slice
    {
      float z = fc2like(tid, p.yh + ks * 512, w2b, xs, red);
      atomicAdd(&st[(tid >> 4) * EE + cg * 16 + (tid & 15)], z);
    }
    gbar4(p.cnt, sidx++);
    // E: nxt = rms(s)@wn + nb; carry inp_{t+1}; persist ssS
    {
      float z = fc1like<4>(tid, cu, st, p.nw, wn, xs, red, ssrow,
                           nullptr, nullptr, nullptr);
      if (cu == 0 && tid < 32) p.ssS[t * 32 + tid] = ssrow[tid];
      if (tid < 128) {
        const int b2 = tid >> 2, m2 = tid & 3, gn = cu * 4 + m2;
        float rinv = rsqrtf(ssrow[b2] * (1.f / EE) + EPSF);
        float nv = z * rinv + p.nxtb[gn];
        stb_f32(&p.nxt_all[(size_t)t * BE + b2 * EE + gn], nv);
        if (t + 1 < TT) {
          int tok = p.tokens[b2 * TT + t + 1];
          stb_f32(&p.inp_all[(size_t)(t + 1) * BE + b2 * EE + gn],
                  p.embw[(size_t)tok * EE + gn] + nv);
        }
      }
    }
    gbar4(p.cnt, sidx++);
  }
}

// ======================= helpers =======================

__global__ void k_zero(float* __restrict__ p, int n) {
  int i = blockIdx.x * 256 + threadIdx.x;
  if (i < n) p[i] = 0.f;
}

__global__ void k_init(const int* __restrict__ tokens,
                       const float* __restrict__ embw,
                       float* __restrict__ inp0) {
  int b = blockIdx.x;
  int tok = tokens[b * TT];
  int e = threadIdx.x * 4;
  float4 v = *(const float4*)&embw[(size_t)tok * EE + e];
  *(float4*)&inp0[b * EE + e] = v;
}

// ======================= legacy fallback (round-1, proven) =======================

__global__ __launch_bounds__(256)
void k_fc1(const float* __restrict__ h, const float* __restrict__ bnw,
           const float* __restrict__ W, const float* __restrict__ bias,
           float* __restrict__ yout, float* __restrict__ initDst,
           const float* __restrict__ initAdd, const float* __restrict__ initBias) {
  __shared__ __align__(16) float Hs[32][68];
  __shared__ __align__(16) float Ws[8][68];
  __shared__ float ssrow[32];
  const int tid = threadIdx.x;
  const int col0 = blockIdx.x * 8;
  const int c = tid & 7;
  const int b = tid >> 3;
  const bool writer = (blockIdx.x == 0);
  float acc = 0.f;
  float ssl[8];
#pragma unroll
  for (int j = 0; j < 8; ++j) ssl[j] = 0.f;
  for (int kc = 0; kc < EE; kc += 64) {
#pragma unroll
    for (int j = 0; j < 8; ++j) {
      int i = tid + j * 256;
      int bb = i >> 6, k = i & 63;
      float v = h[bb * EE + kc + k];
      ssl[j] += v * v;
      Hs[bb][k] = v * bnw[kc + k];
      if (writer) {
        float d = v + initBias[kc + k];
        if (initAdd) d += initAdd[bb * EE + kc + k];
        initDst[bb * EE + kc + k] = d;
      }
    }
#pragma unroll
    for (int j = 0; j < 2; ++j) {
      int i = tid + j * 256;
      int cc = i >> 6, k = i & 63;
      Ws[cc][k] = W[(size_t)(col0 + cc) * EE + kc + k];
    }
    __syncthreads();
#pragma unroll
    for (int k = 0; k < 64; k += 4) {
      float4 w4 = *(const float4*)&Ws[c][k];
      float4 h4 = *(const float4*)&Hs[b][k];
      acc += h4.x * w4.x + h4.y * w4.y + h4.z * w4.z + h4.w * w4.w;
    }
    __syncthreads();
  }
  const int wv = tid >> 6;
#pragma unroll
  for (int j = 0; j < 8; ++j) {
    float v = ssl[j];
#pragma unroll
    for (int off = 32; off > 0; off >>= 1) v += __shfl_xor(v, off);
    if ((tid & 63) == 0) ssrow[wv + 4 * j] = v;
  }
  __syncthreads();
  float rinv = rsqrtf(ssrow[b] * (1.f / EE) + EPSF);
  float z = acc * rinv + bias[col0 + c];
  yout[b * MM + col0 + c] = z / (1.f + expf(-z));
}

__global__ __launch_bounds__(256)
void k_fc2(const float* __restrict__ y, const float* __restrict__ W2,
           float* __restrict__ dest) {
  __shared__ __align__(16) float Ys[32][68];
  __shared__ __align__(16) float Ws[16][68];
  const int tid = threadIdx.x;
  const int cgi = blockIdx.x & 63;
  const int ks = blockIdx.x >> 6;
  const int col0 = cgi * 16;
  const int c = tid & 15;
  const int bq = tid >> 4;
  float acc0 = 0.f, acc1 = 0.f;
  const int kend = ks * 512 + 512;
  for (int kc = ks * 512; kc < kend; kc += 64) {
#pragma unroll
    for (int j = 0; j < 8; ++j) {
      int i = tid + j * 256;
      int bb = i >> 6, k = i & 63;
      Ys[bb][k] = y[bb * MM + kc + k];
    }
#pragma unroll
    for (int j = 0; j < 4; ++j) {
      int i = tid + j * 256;
      int cc = i >> 6, k = i & 63;
      Ws[cc][k] = W2[(size_t)(col0 + cc) * MM + kc + k];
    }
    __syncthreads();
#pragma unroll
    for (int k = 0; k < 64; k += 4) {
      float4 w4 = *(const float4*)&Ws[c][k];
      float4 a4 = *(const float4*)&Ys[bq][k];
      float4 b4 = *(const float4*)&Ys[bq + 16][k];
      acc0 += a4.x * w4.x + a4.y * w4.y + a4.z * w4.z + a4.w * w4.w;
      acc1 += b4.x * w4.x + b4.y * w4.y + b4.z * w4.z + b4.w * w4.w;
    }
    __syncthreads();
  }
  atomicAdd(&dest[bq * EE + col0 + c], acc0);
  atomicAdd(&dest[(bq + 16) * EE + col0 + c], acc1);
}

__global__ __launch_bounds__(256)
void k_nxt(const float* __restrict__ s, const float* __restrict__ nw,
           const float* __restrict__ Wn, const float* __restrict__ nb,
           float* __restrict__ nxt_out, float* __restrict__ ss_out,
           const int* __restrict__ tokens, const float* __restrict__ embw,
           float* __restrict__ inp_next, int tnext) {
  __shared__ __align__(16) float Xs[32][68];
  __shared__ __align__(16) float Ws[8][68];
  __shared__ float ssrow[32];
  const int tid = threadIdx.x;
  const int col0 = blockIdx.x * 8;
  const int c = tid & 7;
  const int b = tid >> 3;
  float acc = 0.f;
  float ssl[8];
#pragma unroll
  for (int j = 0; j < 8; ++j) ssl[j] = 0.f;
  for (int kc = 0; kc < EE; kc += 64) {
#pragma unroll
    for (int j = 0; j < 8; ++j) {
      int i = tid + j * 256;
      int bb = i >> 6, k = i & 63;
      float v = s[bb * EE + kc + k];
      ssl[j] += v * v;
      Xs[bb][k] = v * nw[kc + k];
    }
#pragma unroll
    for (int j = 0; j < 2; ++j) {
      int i = tid + j * 256;
      int cc = i >> 6, k = i & 63;
      Ws[cc][k] = Wn[(size_t)(col0 + cc) * EE + kc + k];
    }
    __syncthreads();
#pragma unroll
    for (int k = 0; k < 64; k += 4) {
      float4 w4 = *(const float4*)&Ws[c][k];
      float4 h4 = *(const float4*)&Xs[b][k];
      acc += h4.x * w4.x + h4.y * w4.y + h4.z * w4.z + h4.w * w4.w;
    }
    __syncthreads();
  }
  const int wv = tid >> 6;
#pragma unroll
  for (int j = 0; j < 8; ++j) {
    float v = ssl[j];
#pragma unroll
    for (int off = 32; off > 0; off >>= 1) v += __shfl_xor(v, off);
    if ((tid & 63) == 0) {
      ssrow[wv + 4 * j] = v;
      if (blockIdx.x == 0) ss_out[wv + 4 * j] = v;
    }
  }
  __syncthreads();
  float rinv = rsqrtf(ssrow[b] * (1.f / EE) + EPSF);
  float nv = acc * rinv + nb[col0 + c];
  nxt_out[b * EE + col0 + c] = nv;
  if (inp_next) {
    int tok = tokens[b * TT + tnext];
    inp_next[b * EE + col0 + c] = embw[(size_t)tok * EE + col0 + c] + nv;
  }
}

// ======================= phase 2 (fp16 dot2) =======================

__global__ __launch_bounds__(256)
void k_curemb(const float* __restrict__ s_all, const float* __restrict__ ss_s,
              const float* __restrict__ nw, const float* __restrict__ Wc,
              const float* __restrict__ cb, const float* __restrict__ inp_all,
              float* __restrict__ cur_out, float* __restrict__ aux_accum) {
  __shared__ __align__(16) h2 Ah[8 * 68];
  __shared__ __align__(16) h2 Bh[8 * 68];
  __shared__ float rr[64];
  __shared__ float wred[4];
  const int tid = threadIdx.x;
  const int rt = blockIdx.x & 127;
  const int ct = blockIdx.x >> 7;
  const int row0 = rt * 64, col0 = ct * 64;
  if (tid < 64) rr[tid] = rsqrtf(ss_s[row0 + tid] * (1.f / EE) + EPSF);
  __syncthreads();
  float acc[4][4];
#pragma unroll
  for (int i = 0; i < 4; ++i)
#pragma unroll
    for (int j = 0; j < 4; ++j) acc[i][j] = 0.f;
  const int tx = tid & 15, ty = tid >> 4;
  for (int kc = 0; kc < EE; kc += 16) {
#pragma unroll
    for (int j = 0; j < 2; ++j) {
      int idx = tid + j * 256;           // 0..511
      int kp = idx & 7, m = idx >> 3;    // m 0..63
      float2 f = *(const float2*)&s_all[(size_t)(row0 + m) * EE + kc + 2 * kp];
      float2 n2 = *(const float2*)&nw[kc + 2 * kp];
      float r = rr[m];
      h2 hv; hv[0] = (_Float16)(f.x * r * n2.x); hv[1] = (_Float16)(f.y * r * n2.y);
      Ah[kp * 68 + m] = hv;
      float2 w2 = *(const float2*)&Wc[(size_t)(col0 + m) * EE + kc + 2 * kp];
      h2 hw; hw[0] = (_Float16)w2.x; hw[1] = (_Float16)w2.y;
      Bh[kp * 68 + m] = hw;
    }
    __syncthreads();
#pragma unroll
    for (int kp = 0; kp < 8; ++kp) {
      h2 a0 = Ah[kp*68 + tx*4 + 0], a1 = Ah[kp*68 + tx*4 + 1];
      h2 a2 = Ah[kp*68 + tx*4 + 2], a3 = Ah[kp*68 + tx*4 + 3];
      h2 b0 = Bh[kp*68 + ty*4 + 0], b1 = Bh[kp*68 + ty*4 + 1];
      h2 b2 = Bh[kp*68 + ty*4 + 2], b3 = Bh[kp*68 + ty*4 + 3];
      acc[0][0]=dot2f(a0,b0,acc[0][0]); acc[0][1]=dot2f(a0,b1,acc[0][1]);
      acc[0][2]=dot2f(a0,b2,acc[0][2]); acc[0][3]=dot2f(a0,b3,acc[0][3]);
      acc[1][0]=dot2f(a1,b0,acc[1][0]); acc[1][1]=dot2f(a1,b1,acc[1][1]);
      acc[1][2]=dot2f(a1,b2,acc[1][2]); acc[1][3]=dot2f(a1,b3,acc[1][3]);
      acc[2][0]=dot2f(a2,b0,acc[2][0]); acc[2][1]=dot2f(a2,b1,acc[2][1]);
      acc[2][2]=dot2f(a2,b2,acc[2][2]); acc[2][3]=dot2f(a2,b3,acc[2][3]);
      acc[3][0]=dot2f(a3,b0,acc[3][0]); acc[3][1]=dot2f(a3,b1,acc[3][1]);
      acc[3][2]=dot2f(a3,b2,acc[3][2]); acc[3][3]=dot2f(a3,b3,acc[3][3]);
    }
    __syncthreads();
  }
  float auxp = 0.f;
#pragma unroll
  for (int i = 0; i < 4; ++i) {
    int r = row0 + tx * 4 + i;
#pragma unroll
    for (int j = 0; j < 4; ++j) {
      int col = col0 + ty * 4 + j;
      float v = acc[i][j] + cb[col];
      cur_out[(size_t)r * EE + col] = v;
      float d = v - inp_all[(size_t)r * EE + col];
      auxp += d * d;
    }
  }
#pragma unroll
  for (int off = 32; off > 0; off >>= 1) auxp += __shfl_xor(auxp, off);
  if ((tid & 63) == 0) wred[tid >> 6] = auxp;
  __syncthreads();
  if (tid == 0) atomicAdd(aux_accum, wred[0] + wred[1] + wred[2] + wred[3]);
}

__global__ __launch_bounds__(256)
void k_logits(const float* __restrict__ A, const float* __restrict__ embw,
              const int* __restrict__ idxs, float* __restrict__ rowsum,
              float* __restrict__ lidx, float* __restrict__ store) {
  __shared__ __align__(16) h2 Ah[8 * 68];
  __shared__ __align__(16) h2 Bh[8 * 68];
  __shared__ float rowpart[64];
  const int tid = threadIdx.x;
  const int rt = blockIdx.x & 127;
  const int ct = blockIdx.x >> 7;
  const int row0 = rt * 64, col0 = ct * 64;
  float acc[4][4];
#pragma unroll
  for (int i = 0; i < 4; ++i)
#pragma unroll
    for (int j = 0; j < 4; ++j) acc[i][j] = 0.f;
  const int tx = tid & 15, ty = tid >> 4;
  for (int kc = 0; kc < EE; kc += 16) {
#pragma unroll
    for (int j = 0; j < 2; ++j) {
      int idx = tid + j * 256;
      int kp = idx & 7, m = idx >> 3;
      float2 f = *(const float2*)&A[(size_t)(row0 + m) * EE + kc + 2 * kp];
      h2 hv; hv[0] = (_Float16)f.x; hv[1] = (_Float16)f.y;
      Ah[kp * 68 + m] = hv;
      float2 w2 = *(const float2*)&embw[(size_t)(col0 + m) * EE + kc + 2 * kp];
      h2 hw; hw[0] = (_Float16)w2.x; hw[1] = (_Float16)w2.y;
      Bh[kp * 68 + m] = hw;
    }
    __syncthreads();
#pragma unroll
    for (int kp = 0; kp < 8; ++kp) {
      h2 a0 = Ah[kp*68 + tx*4 + 0], a1 = Ah[kp*68 + tx*4 + 1];
      h2 a2 = Ah[kp*68 + tx*4 + 2], a3 = Ah[kp*68 + tx*4 + 3];
      h2 b0 = Bh[kp*68 + ty*4 + 0], b1 = Bh[kp*68 + ty*4 + 1];
      h2 b2 = Bh[kp*68 + ty*4 + 2], b3 = Bh[kp*68 + ty*4 + 3];
      acc[0][0]=dot2f(a0,b0,acc[0][0]); acc[0][1]=dot2f(a0,b1,acc[0][1]);
      acc[0][2]=dot2f(a0,b2,acc[0][2]); acc[0][3]=dot2f(a0,b3,acc[0][3]);
      acc[1][0]=dot2f(a1,b0,acc[1][0]); acc[1][1]=dot2f(a1,b1,acc[1][1]);
      acc[1][2]=dot2f(a1,b2,acc[1][2]); acc[1][3]=dot2f(a1,b3,acc[1][3]);
      acc[2][0]=dot2f(a2,b0,acc[2][0]); acc[2][1]=dot2f(a2,b1,acc[2][1]);
      acc[2][2]=dot2f(a2,b2,acc[2][2]); acc[2][3]=dot2f(a2,b3,acc[2][3]);
      acc[3][0]=dot2f(a3,b0,acc[3][0]); acc[3][1]=dot2f(a3,b1,acc[3][1]);
      acc[3][2]=dot2f(a3,b2,acc[3][2]); acc[3][3]=dot2f(a3,b3,acc[3][3]);
    }
    __syncthreads();
  }
  if (tid < 64) rowpart[tid] = 0.f;
  __syncthreads();
#pragma unroll
  for (int i = 0; i < 4; ++i) {
    int r = row0 + tx * 4 + i;
    int t = r >> 5, bb = r & 31;
    int idx = idxs[bb * TT + t];
    float e0 = expf(acc[i][0]);
    float e1 = expf(acc[i][1]);
    float e2 = expf(acc[i][2]);
    float e3 = expf(acc[i][3]);
    atomicAdd(&rowpart[tx * 4 + i], e0 + e1 + e2 + e3);
    int cbase = col0 + ty * 4;
#pragma unroll
    for (int j = 0; j < 4; ++j)
      if (cbase + j == idx) lidx[r] = acc[i][j];
    if (store) {
      float4 o = make_float4(acc[i][0], acc[i][1], acc[i][2], acc[i][3]);
      *(float4*)(store + ((size_t)bb * TT + t) * VV + cbase) = o;
    }
  }
  __syncthreads();
  if (tid < 64) atomicAdd(&rowsum[row0 + tid], rowpart[tid]);
}

__global__ void k_final(const float* __restrict__ rs_cur,
                        const float* __restrict__ rs_nxt,
                        const float* __restrict__ ltok,
                        const float* __restrict__ ltgt,
                        const float* __restrict__ aux_accum,
                        float* __restrict__ out) {
  float p = 0.f;
  for (int r = threadIdx.x; r < NROWS; r += 256)
    p += (ltok[r] - logf(rs_cur[r])) + (ltgt[r] - logf(rs_nxt[r]));
#pragma unroll
  for (int off = 32; off > 0; off >>= 1) p += __shfl_xor(p, off);
  __shared__ float w[4];
  if ((threadIdx.x & 63) == 0) w[threadIdx.x >> 6] = p;
  __syncthreads();
  if (threadIdx.x == 0) {
    float tot = w[0] + w[1] + w[2] + w[3];
    out[0] = -tot / (2.f * (float)NROWS);
    out[1] = aux_accum[0] * (1.f / ((float)NROWS * EE));
  }
}

// ======================= launch =======================

extern "C" void kernel_launch(void* const* d_in, const int* in_sizes, int n_in,
                              void* d_out, int out_size, void* d_ws, size_t ws_size,
                              hipStream_t stream) {
  (void)in_sizes; (void)n_in; (void)out_size; (void)ws_size;
  const int*   tokens  = (const int*)d_in[0];
  const int*   targets = (const int*)d_in[1];
  const float* embw    = (const float*)d_in[2];
  const float* bnw     = (const float*)d_in[3];
  const float* fc1w    = (const float*)d_in[4];
  const float* fc1b    = (const float*)d_in[5];
  const float* fc2w    = (const float*)d_in[6];
  const float* fc2b    = (const float*)d_in[7];
  const float* nw      = (const float*)d_in[8];
  const float* curw    = (const float*)d_in[9];
  const float* curb    = (const float*)d_in[10];
  const float* nxtw    = (const float*)d_in[11];
  const float* nxtb    = (const float*)d_in[12];
  float* out = (float*)d_out;

  // d_out quadrants (each 8,388,608 floats); all overwritten by final k_logits
  float* cur_all  = out;
  float* s_all    = out + (size_t)NROWS * EE;
  float* inp_all  = out + 2 * (size_t)NROWS * EE;
  float* hbuf_all = out + 3 * (size_t)NROWS * EE;

  float* ws       = (float*)d_ws;
  float* nxt_all  = ws;                       // 8,388,608
  float* ltok     = ws + 8388608;             // 8,192
  float* ltgt     = ws + 8396800;             // 8,192
  unsigned* yh    = (unsigned*)(ws + 8404992);// 65,536 u32
  float* rs_cur   = ws + 8470528;             // 8,192
  float* rs_nxt   = ws + 8478720;             // 8,192
  float* auxac    = ws + 8486912;             // 1 (+pad)
  unsigned* cnt   = (unsigned*)(ws + 8486944);// 1280*17*32 = 696,320
  float* ssS      = ws + 9183264;             // 8,192
  float* ybuf     = ws + 9191456;             // 131,072 (fallback)

  // zero rs_cur..auxac+pad + counters (contiguous span)
  const int nzero = (8486944 + 696320) - 8470528;
  k_zero<<<(nzero + 255) / 256, 256, 0, stream>>>(rs_cur, nzero);
  k_init<<<32, 256, 0, stream>>>(tokens, embw, inp_all);

  Scan4Params p;
  p.tokens = tokens; p.embw = embw; p.bnw = bnw;
  p.fc1w = fc1w; p.fc1b = fc1b; p.fc2w = fc2w; p.fc2b = fc2b;
  p.nw = nw; p.nxtw = nxtw; p.nxtb = nxtb;
  p.inp_all = inp_all; p.s_all = s_all; p.hbuf_all = hbuf_all;
  p.nxt_all = nxt_all; p.yh = yh; p.ssS = ssS; p.cnt = cnt;

  const size_t shmem = 156800;
  hipError_t err = hipFuncSetAttribute((const void*)k_scan4,
      hipFuncAttributeMaxDynamicSharedMemorySize, (int)shmem);
  if (err == hipSuccess) {
    void* args[] = { &p };
    err = hipLaunchCooperativeKernel((const void*)k_scan4, dim3(256), dim3(512),
                                     args, shmem, stream);
  }
  if (err != hipSuccess) {
    // fallback: proven round-1 multi-kernel sequence (fp32)
    float* hbuf = hbuf_all;  // single reused buffer
    for (int t = 0; t < TT; ++t) {
      const float* inp = inp_all + (size_t)t * BE;
      float* s = s_all + (size_t)t * BE;
      k_fc1<<<512, 256, 0, stream>>>(inp, bnw, fc1w, fc1b, ybuf,
                                     hbuf, nullptr, fc2b);
      k_fc2<<<512, 256, 0, stream>>>(ybuf, fc2w, hbuf);
      k_fc1<<<512, 256, 0, stream>>>(hbuf, bnw + EE, fc1w + (size_t)MM * EE,
                                     fc1b + MM, ybuf, s, inp, fc2b + EE);
      k_fc2<<<512, 256, 0, stream>>>(ybuf, fc2w + (size_t)EE * MM, s);
      k_nxt<<<128, 256, 0, stream>>>(s, nw, nxtw, nxtb,
                                     nxt_all + (size_t)t * BE, ssS + t * BB,
                                     tokens, embw,
                                     (t + 1 < TT) ? inp_all + (size_t)(t + 1) * BE : nullptr,
                                     t + 1);
    }
  }

  k_curemb<<<2048, 256, 0, stream>>>(s_all, ssS, nw, curw, curb, inp_all,
                                     cur_all, auxac);
  k_logits<<<8192, 256, 0, stream>>>(cur_all, embw, tokens, rs_cur, ltok, nullptr);
  k_logits<<<8192, 256, 0, stream>>>(nxt_all, embw, targets, rs_nxt, ltgt, out);
  k_final<<<1, 256, 0, stream>>>(rs_cur, rs_nxt, ltok, ltgt, auxac,
                                 out + (size_t)NROWS * VV);
}